// Round 1
// 162.276 us; speedup vs baseline: 1.0344x; 1.0344x over previous
//
#include <hip/hip_runtime.h>
#include <stdint.h>

#define S_LEN 2048
#define EMBED 1024
#define HEADS 16
#define HD 64
#define M_ROWS 4096      // B*S
#define N_QKV 3072
#define KDIM 1024
#define SP 2336          // padded vT row length: 128 + 2048 + 160
#define CLP2 200         // qkv C-tile LDS col stride (u16)

typedef __attribute__((ext_vector_type(8))) short short8;
typedef __attribute__((ext_vector_type(4))) float f32x4;

__device__ __forceinline__ unsigned short f2bf(float f) {
  union { float f; uint32_t u; } c; c.f = f;
  uint32_t u = c.u;
  u += 0x7fffu + ((u >> 16) & 1u);  // round-to-nearest-even
  return (unsigned short)(u >> 16);
}

// async global->LDS, 16B per lane; lds base must be wave-uniform (HW adds lane*16)
__device__ __forceinline__ void gload_lds16(const unsigned short* g, unsigned short* l) {
  __builtin_amdgcn_global_load_lds(
      (const __attribute__((address_space(1))) void*)g,
      (__attribute__((address_space(3))) void*)l, 16, 0, 0);
}

// ---------------- fused fp32->bf16 convert (x, Wqkv, Wo) + vT halo zero ----------------
#define XQ 1048576
#define WQKVQ 786432
#define WOQ 262144
#define CVTQ (XQ + WQKVQ + WOQ)      // 2,097,152 quads
__global__ __launch_bounds__(256) void cvt3_kernel(
    const float* __restrict__ x, const float* __restrict__ wqkv, const float* __restrict__ wo,
    unsigned short* __restrict__ xb, unsigned short* __restrict__ wqkvb, unsigned short* __restrict__ wob,
    unsigned short* __restrict__ vTp) {
  int i = blockIdx.x * blockDim.x + threadIdx.x;
  if (i < CVTQ) {
    const float* s; unsigned short* d; int off;
    if (i < XQ)               { s = x;    d = xb;    off = i; }
    else if (i < XQ + WQKVQ)  { s = wqkv; d = wqkvb; off = i - XQ; }
    else                      { s = wo;   d = wob;   off = i - XQ - WQKVQ; }
    float4 f = reinterpret_cast<const float4*>(s)[off];
    ushort4 o;
    o.x = f2bf(f.x); o.y = f2bf(f.y); o.z = f2bf(f.z); o.w = f2bf(f.w);
    reinterpret_cast<ushort4*>(d)[off] = o;
  } else {
    int j = i - CVTQ;                      // 0..147455
    int row = j / 72, p = j % 72;          // row = bh*64+d
    int off = row * 584 + (p < 32 ? p : 544 + (p - 32));  // left 128 u16 / right 160 u16
    reinterpret_cast<ushort4*>(vTp)[off] = (ushort4){0, 0, 0, 0};
  }
}

// ---------------- QKV GEMM: 128x192 head-aligned tiles, BK=64, 2-phase dbuf ----------------
// nb = head (0..15): cols = [q 0..63 | k 64..127 | v 128..191] of head nb.
// 512 blocks, bid%8 = nb%8 -> head's home XCD matches attn's bh%8 swizzle.
// T3-min pipeline: issue next K-tile's global_load_lds BEFORE current tile's
// ds_read+MFMA; single barrier/K-step drains vmcnt after compute has covered the latency.
__global__ __launch_bounds__(256) void gemm_qkv(
    const unsigned short* __restrict__ A, const unsigned short* __restrict__ Bm,
    const float* __restrict__ bias, const int* __restrict__ pm,
    unsigned short* __restrict__ qo, unsigned short* __restrict__ ko,
    unsigned short* __restrict__ vTp)
{
  // staging: 2 bufs x (As 128x64 + Bs 192x64) u16 = 81,920 B (2 blocks/CU = exactly 160 KiB)
  // epilogue reuse: Cld[128][CLP2] = 25,600 u16 aliased over the staging region
  __shared__ __align__(16) unsigned short smem[40960];
  const int t = threadIdx.x, wave = t >> 6, lane = t & 63;
  const int m16 = lane & 15, q4 = lane >> 4;
  const int wm = wave >> 1, wn = wave & 1;          // 2x2 waves, each 64 rows x 96 cols
  const int bid = blockIdx.x;
  const int mb = bid >> 4, nb = bid & 15;           // nb = head; XCD = nb%8
  const int srow = lane >> 2, scol = (lane & 3) << 3;
  const unsigned short* pA0 = A + (size_t)(mb * 128 + wave * 32 + srow) * KDIM + scol;
  const unsigned short* pA1 = pA0 + 16 * KDIM;
  const unsigned short* pB0 = Bm + (size_t)(nb * 192 + wave * 48 + srow) * KDIM + scol;
  const unsigned short* pB1 = pB0 + 16 * KDIM;
  const unsigned short* pB2 = pB0 + 32 * KDIM;
  f32x4 acc[4][6];
#pragma unroll
  for (int i_ = 0; i_ < 4; i_++)
#pragma unroll
    for (int j_ = 0; j_ < 6; j_++) acc[i_][j_] = (f32x4){0.f, 0.f, 0.f, 0.f};

  auto stage = [&](int buf, int kt) {
    unsigned short* As = smem + buf * 20480;
    unsigned short* Bs = As + 8192;
#pragma unroll
    for (int h = 0; h < 2; h++) {
      gload_lds16(pA0 + kt + h * 32, As + h * 4096 + (wave * 32) * 32);
      gload_lds16(pA1 + kt + h * 32, As + h * 4096 + (wave * 32 + 16) * 32);
      gload_lds16(pB0 + kt + h * 32, Bs + h * 6144 + (wave * 48) * 32);
      gload_lds16(pB1 + kt + h * 32, Bs + h * 6144 + (wave * 48 + 16) * 32);
      gload_lds16(pB2 + kt + h * 32, Bs + h * 6144 + (wave * 48 + 32) * 32);
    }
  };

  // prologue: stage K-tile 0 into buffer 0
  stage(0, 0);
  __syncthreads();           // vmcnt(0) drain: buf0 ready
  int cur = 0;
  for (int kt = 0; kt < KDIM; kt += 64) {
    if (kt + 64 < KDIM) stage(cur ^ 1, kt + 64);   // prefetch flies during compute
    const unsigned short* As = smem + cur * 20480;
    const unsigned short* Bs = As + 8192;
#pragma unroll
    for (int h = 0; h < 2; h++) {
      short8 af[4], bf[6];
#pragma unroll
      for (int mt = 0; mt < 4; mt++)
        af[mt] = *reinterpret_cast<const short8*>(&As[h * 4096 + (wm * 64 + mt * 16 + m16) * 32 + q4 * 8]);
#pragma unroll
      for (int nt = 0; nt < 6; nt++)
        bf[nt] = *reinterpret_cast<const short8*>(&Bs[h * 6144 + (wn * 96 + nt * 16 + m16) * 32 + q4 * 8]);
#pragma unroll
      for (int mt = 0; mt < 4; mt++)
#pragma unroll
        for (int nt = 0; nt < 6; nt++)
          acc[mt][nt] = __builtin_amdgcn_mfma_f32_16x16x32_bf16(af[mt], bf[nt], acc[mt][nt], 0, 0, 0);
    }
    __syncthreads();         // drains prefetch vmcnt + all frag reads of buf[cur]
    cur ^= 1;
  }

  // loop-final barrier covers frag reads; smem may now be reused as Cld
  float pmv[4][4];
#pragma unroll
  for (int mt = 0; mt < 4; mt++)
#pragma unroll
    for (int reg = 0; reg < 4; reg++) {
      int row = mb * 128 + wm * 64 + mt * 16 + q4 * 4 + reg;
      pmv[mt][reg] = (pm[row] != 0) ? 0.0f : 1.0f;
    }
#pragma unroll
  for (int nt = 0; nt < 6; nt++) {
    int cloc = wn * 96 + nt * 16 + m16;
    float bv = bias[nb * 192 + cloc];
#pragma unroll
    for (int mt = 0; mt < 4; mt++) {
#pragma unroll
      for (int reg = 0; reg < 4; reg++) {
        int rloc = wm * 64 + mt * 16 + q4 * 4 + reg;
        smem[rloc * CLP2 + cloc] = f2bf((acc[mt][nt][reg] + bv) * pmv[mt][reg]);
      }
    }
  }
  __syncthreads();
  const int s0 = mb * 128;                 // 128-row tiles never cross the 2048 batch boundary
  const int bh = (s0 >> 11) * 16 + nb, s0l = s0 & 2047;
  // q/k writeout: thread -> (row r of 128, 32-col half): 64 B q + 64 B k
  {
    int r = t >> 1, half = t & 1;
    const unsigned short* sq = &smem[r * CLP2 + half * 32];
    unsigned short* dq = qo + ((size_t)(bh * 2048 + s0l + r)) * 64 + half * 32;
#pragma unroll
    for (int j = 0; j < 4; j++)
      *reinterpret_cast<short8*>(dq + j * 8) = *reinterpret_cast<const short8*>(sq + j * 8);
    const unsigned short* sk = &smem[r * CLP2 + 64 + half * 32];
    unsigned short* dk = ko + ((size_t)(bh * 2048 + s0l + r)) * 64 + half * 32;
#pragma unroll
    for (int j = 0; j < 4; j++)
      *reinterpret_cast<short8*>(dk + j * 8) = *reinterpret_cast<const short8*>(sk + j * 8);
  }
  // vT writeout: thread -> (d = t&63, 32-row quarter): 64 B contiguous in s
  {
    int d = t & 63, qtr = t >> 6;
    unsigned short* dst = vTp + (size_t)(bh * 64 + d) * SP + 128 + s0l + qtr * 32;
#pragma unroll
    for (int j8 = 0; j8 < 4; j8++) {
      short8 tmp;
#pragma unroll
      for (int jj = 0; jj < 8; jj++)
        tmp[jj] = (short)smem[(qtr * 32 + j8 * 8 + jj) * CLP2 + 128 + d];
      *reinterpret_cast<short8*>(dst + j8 * 8) = tmp;
    }
  }
}

// ---------------- output projection: 64x128 tile, BK=64, 2-phase dbuf ----------------
// 512 blocks = 2/CU.
__global__ __launch_bounds__(256) void gemm_out(
    const unsigned short* __restrict__ A, const unsigned short* __restrict__ Bm,
    const float* __restrict__ bias, float* __restrict__ out)
{
  // staging: 2 bufs x (As 64x64 + Bs 128x64) u16 = 49,152 B
  // epilogue: Cldf [64][132] f32 = 33,792 B aliased over staging
  __shared__ __align__(16) unsigned char smemraw[49152];
  float* Cldf = (float*)smemraw;
  const int t = threadIdx.x, wave = t >> 6, lane = t & 63;
  const int m16 = lane & 15, q4 = lane >> 4;
  const int wm = wave >> 1, wn = wave & 1;                // 2x2 waves: 32 rows x 64 cols each
  const int flat = blockIdx.y * 8 + blockIdx.x;
  const int xcd = flat & 7, bi = flat >> 3;
  const int mb = xcd * 8 + (bi & 7);                      // per XCD: 8 mb x 8 nb
  const int nb = bi >> 3;
  const int srow = lane >> 2, scol = (lane & 3) << 3;
  const unsigned short* pA  = A + (size_t)(mb * 64 + wave * 16 + srow) * KDIM + scol;
  const unsigned short* pB0 = Bm + (size_t)(nb * 128 + wave * 32 + srow) * KDIM + scol;
  const unsigned short* pB1 = pB0 + 16 * KDIM;
  f32x4 acc[2][4];
#pragma unroll
  for (int i_ = 0; i_ < 2; i_++)
#pragma unroll
    for (int j_ = 0; j_ < 4; j_++) acc[i_][j_] = (f32x4){0.f, 0.f, 0.f, 0.f};

  auto stage = [&](int buf, int kt) {
    unsigned short* As = (unsigned short*)smemraw + buf * 12288;
    unsigned short* Bs = As + 4096;
#pragma unroll
    for (int h = 0; h < 2; h++) {
      gload_lds16(pA + kt + h * 32,  As + h * 2048 + (wave * 16) * 32);
      gload_lds16(pB0 + kt + h * 32, Bs + h * 4096 + (wave * 32) * 32);
      gload_lds16(pB1 + kt + h * 32, Bs + h * 4096 + (wave * 32 + 16) * 32);
    }
  };

  stage(0, 0);
  __syncthreads();
  int cur = 0;
  for (int kt = 0; kt < KDIM; kt += 64) {
    if (kt + 64 < KDIM) stage(cur ^ 1, kt + 64);
    const unsigned short* As = (const unsigned short*)smemraw + cur * 12288;
    const unsigned short* Bs = As + 4096;
#pragma unroll
    for (int h = 0; h < 2; h++) {
      short8 af[2], bf[4];
#pragma unroll
      for (int mt = 0; mt < 2; mt++)
        af[mt] = *reinterpret_cast<const short8*>(&As[h * 2048 + (wm * 32 + mt * 16 + m16) * 32 + q4 * 8]);
#pragma unroll
      for (int nt = 0; nt < 4; nt++)
        bf[nt] = *reinterpret_cast<const short8*>(&Bs[h * 4096 + (wn * 64 + nt * 16 + m16) * 32 + q4 * 8]);
#pragma unroll
      for (int mt = 0; mt < 2; mt++)
#pragma unroll
        for (int nt = 0; nt < 4; nt++)
          acc[mt][nt] = __builtin_amdgcn_mfma_f32_16x16x32_bf16(af[mt], bf[nt], acc[mt][nt], 0, 0, 0);
    }
    __syncthreads();
    cur ^= 1;
  }

#pragma unroll
  for (int nt = 0; nt < 4; nt++) {
    int cloc = wn * 64 + nt * 16 + m16;
    float bv = bias[nb * 128 + cloc];
#pragma unroll
    for (int mt = 0; mt < 2; mt++) {
#pragma unroll
      for (int reg = 0; reg < 4; reg++) {
        int rloc = wm * 32 + mt * 16 + q4 * 4 + reg;
        Cldf[rloc * 132 + cloc] = acc[mt][nt][reg] + bv;
      }
    }
  }
  __syncthreads();
  {
    int r = t >> 2, seg = t & 3;   // 64 rows x 4 segments of 32 floats (128 B)
    float* dst = out + (size_t)(mb * 64 + r) * EMBED + nb * 128 + seg * 32;
    const float* srcl = &Cldf[r * 132 + seg * 32];
#pragma unroll
    for (int j = 0; j < 8; j++)
      *reinterpret_cast<float4*>(dst + j * 4) = *reinterpret_cast<const float4*>(srcl + j * 4);
  }
}

// ---------------- banded attention v3: bulk LDS staging, branch-free ----------------
__global__ __launch_bounds__(256, 2) void attn_kernel(
    const unsigned short* __restrict__ q, const unsigned short* __restrict__ k,
    const unsigned short* __restrict__ vTp, unsigned short* __restrict__ vals)
{
  __shared__ __align__(16) unsigned short smem[40960];   // 81,920 B
  unsigned short* Ks = smem;            // [320][64] u16 (40,960 B)
  unsigned short* Vs = smem + 20480;    // [64][320] u16 (40,960 B)
  unsigned short* Pld = smem;           // alias over Ks after QK phase: [4][16][296]

  const int bid = blockIdx.x;
  const int bh = bid & 31, qg = bid >> 5;                // bh-fastest: XCD-local K/V
  const int lane = threadIdx.x & 63, wave = threadIdx.x >> 6;
  const int i0b = qg * 64;
  const int i0 = i0b + wave * 16;
  const int m16 = lane & 15, q4 = lane >> 4;

  // ---- stage K window: 40 KB = 40 wave-issues of 1 KB (10 per wave) ----
  const unsigned short* kbase = k + (size_t)bh * 2048 * 64;
#pragma unroll
  for (int n = 0; n < 10; n++) {
    int idx = (n * 4 + wave) * 64 + lane;      // 0..2559
    int krow = idx >> 3, seg = idx & 7;
    int grow = i0b - 128 + krow;
    grow = grow < 0 ? 0 : (grow > 2047 ? 2047 : grow);
    int lseg = seg ^ (krow & 7);               // store swizzled within 128B row
    gload_lds16(kbase + (size_t)grow * 64 + lseg * 8, Ks + (n * 4 + wave) * 512);
  }
  // ---- stage V^T window: 40 KB, rows of 320 u16 (40 segs of 16B) ----
  const unsigned short* vbase = vTp + (size_t)bh * 64 * SP + i0b;  // col(i0b) == key i0b-128
#pragma unroll
  for (int n = 0; n < 10; n++) {
    int idx = (n * 4 + wave) * 64 + lane;      // 0..2559
    int vrow = idx / 40, rem = idx % 40;
    int l = (rem & ~7) | ((rem & 7) ^ (vrow & 7));
    gload_lds16(vbase + (size_t)vrow * SP + l * 8, Vs + (n * 4 + wave) * 512);
  }

  // q fragments (direct, tiny)
  const unsigned short* qb = q + ((size_t)(bh * 2048 + i0 + m16)) * 64 + q4 * 8;
  short8 aq0 = *reinterpret_cast<const short8*>(qb);
  short8 aq1 = *reinterpret_cast<const short8*>(qb + 32);

  __syncthreads();

  // ---- QK^T + streaming exp, P packed in registers ----
  float sum[4] = {0.f, 0.f, 0.f, 0.f};
  uint32_t pP[18][2];
#pragma unroll
  for (int ct = 0; ct < 18; ct++) {
    int r = (wave + ct) * 16 + m16;            // LDS key row (may run past 320: finite data, masked)
    int js = i0b - 128 + r;                    // global key index
    const unsigned short* kr = Ks + r * 64;
    short8 b0 = *reinterpret_cast<const short8*>(kr + ((q4 ^ (r & 7)) * 8));
    short8 b1 = *reinterpret_cast<const short8*>(kr + (((q4 + 4) ^ (r & 7)) * 8));
    f32x4 a = {0.f, 0.f, 0.f, 0.f};
    a = __builtin_amdgcn_mfma_f32_16x16x32_bf16(aq0, b0, a, 0, 0, 0);
    a = __builtin_amdgcn_mfma_f32_16x16x32_bf16(aq1, b1, a, 0, 0, 0);
    unsigned short pe[4];
#pragma unroll
    for (int reg = 0; reg < 4; reg++) {
      int i = i0 + q4 * 4 + reg;
      bool valid = (js >= 0) && (js < 2048) && (js >= i - 128) && (js <= i + 128);
      float e = valid ? __expf(a[reg] * 0.125f) : 0.0f;
      sum[reg] += e;
      pe[reg] = f2bf(e);
    }
    pP[ct][0] = (uint32_t)pe[0] | ((uint32_t)pe[1] << 16);
    pP[ct][1] = (uint32_t)pe[2] | ((uint32_t)pe[3] << 16);
  }
  float rden[4];
#pragma unroll
  for (int reg = 0; reg < 4; reg++) {
    float s = sum[reg];
    s += __shfl_xor(s, 1);
    s += __shfl_xor(s, 2);
    s += __shfl_xor(s, 4);
    s += __shfl_xor(s, 8);
    rden[reg] = 1.0f / s;
  }

  __syncthreads();   // all Ks reads done; Pld may now overwrite Ks

  unsigned short* Pw = Pld + wave * 16 * 296;
#pragma unroll
  for (int ct = 0; ct < 18; ct++) {
    Pw[(q4 * 4 + 0) * 296 + ct * 16 + m16] = (unsigned short)(pP[ct][0] & 0xFFFF);
    Pw[(q4 * 4 + 1) * 296 + ct * 16 + m16] = (unsigned short)(pP[ct][0] >> 16);
    Pw[(q4 * 4 + 2) * 296 + ct * 16 + m16] = (unsigned short)(pP[ct][1] & 0xFFFF);
    Pw[(q4 * 4 + 3) * 296 + ct * 16 + m16] = (unsigned short)(pP[ct][1] >> 16);
  }
  // own-wave LDS ordering handled by lgkmcnt; no block barrier needed
  short8 ap[9];
#pragma unroll
  for (int kc = 0; kc < 9; kc++)
    ap[kc] = *reinterpret_cast<const short8*>(&Pw[m16 * 296 + kc * 32 + q4 * 8]);

  const int b = bh >> 4, h = bh & 15;
#pragma unroll
  for (int dt = 0; dt < 4; dt++) {
    int vrow = dt * 16 + m16;
    const unsigned short* vr = Vs + vrow * 320;
    f32x4 av = {0.f, 0.f, 0.f, 0.f};
#pragma unroll
    for (int kc = 0; kc < 9; kc++) {
      int jseg = kc * 4 + wave * 2 + q4;       // logical 16B seg within V^T row
      if (jseg > 39) jseg = 39;                // clamp: clamped segs have P==0
      int sseg = (jseg & ~7) | ((jseg & 7) ^ (vrow & 7));
      short8 bv = *reinterpret_cast<const short8*>(vr + sseg * 8);
      av = __builtin_amdgcn_mfma_f32_16x16x32_bf16(ap[kc], bv, av, 0, 0, 0);
    }
#pragma unroll
    for (int reg = 0; reg < 4; reg++)
      Pw[(q4 * 4 + reg) * 296 + dt * 16 + m16] = f2bf(av[reg] * rden[reg]);
  }
  // coalesced O writeout: 4 lanes x 32B per row -> full 128B lines
  {
    int srow = lane >> 2, seg = lane & 3;
    unsigned short* dst = vals + ((size_t)(b * 2048 + i0 + srow)) * 1024 + h * 64 + seg * 16;
    const unsigned short* srcl = &Pw[srow * 296 + seg * 16];
    *reinterpret_cast<short8*>(dst)     = *reinterpret_cast<const short8*>(srcl);
    *reinterpret_cast<short8*>(dst + 8) = *reinterpret_cast<const short8*>(srcl + 8);
  }
}

extern "C" void kernel_launch(void* const* d_in, const int* in_sizes, int n_in,
                              void* d_out, int out_size, void* d_ws, size_t ws_size,
                              hipStream_t stream) {
  const float* x    = (const float*)d_in[0];
  const int*   pm   = (const int*)d_in[1];
  const float* Wqkv = (const float*)d_in[2];
  const float* bqkv = (const float*)d_in[3];
  const float* Wo   = (const float*)d_in[4];
  const float* bo   = (const float*)d_in[5];
  float* out = (float*)d_out;
  char* ws = (char*)d_ws;

  unsigned short* xb    = (unsigned short*)(ws);                 //  8,388,608
  unsigned short* vals  = (unsigned short*)(ws);                 //  reuse (xb dead after gemm_qkv)
  unsigned short* Wqkvb = (unsigned short*)(ws +  8388608);      //  6,291,456
  unsigned short* Wob   = (unsigned short*)(ws + 14680064);      //  2,097,152
  unsigned short* qbuf  = (unsigned short*)(ws + 16777216);      //  8,388,608
  unsigned short* kbuf  = (unsigned short*)(ws + 25165824);      //  8,388,608
  unsigned short* vTp   = (unsigned short*)(ws + 33554432);      //  9,568,256 (ends 43,122,688)

  cvt3_kernel<<<8768, 256, 0, stream>>>(x, Wqkv, Wo, xb, Wqkvb, Wob, vTp);
  gemm_qkv<<<512, 256, 0, stream>>>(xb, Wqkvb, bqkv, pm, qbuf, kbuf, vTp);
  attn_kernel<<<1024, 256, 0, stream>>>(qbuf, kbuf, vTp, vals);
  gemm_out<<<dim3(8, 64), 256, 0, stream>>>(vals, Wob, bo, out);
}

// Round 2
// 161.060 us; speedup vs baseline: 1.0422x; 1.0076x over previous
//
#include <hip/hip_runtime.h>
#include <stdint.h>

#define S_LEN 2048
#define EMBED 1024
#define HEADS 16
#define HD 64
#define M_ROWS 4096      // B*S
#define N_QKV 3072
#define KDIM 1024
#define SP 2336          // padded vT row length: 128 + 2048 + 160
#define CLP2 200         // qkv C-tile LDS col stride (u16)

typedef __attribute__((ext_vector_type(8))) short short8;
typedef __attribute__((ext_vector_type(4))) float f32x4;

__device__ __forceinline__ unsigned short f2bf(float f) {
  union { float f; uint32_t u; } c; c.f = f;
  uint32_t u = c.u;
  u += 0x7fffu + ((u >> 16) & 1u);  // round-to-nearest-even
  return (unsigned short)(u >> 16);
}

// async global->LDS, 16B per lane; lds base must be wave-uniform (HW adds lane*16)
__device__ __forceinline__ void gload_lds16(const unsigned short* g, unsigned short* l) {
  __builtin_amdgcn_global_load_lds(
      (const __attribute__((address_space(1))) void*)g,
      (__attribute__((address_space(3))) void*)l, 16, 0, 0);
}

// ---------------- fused fp32->bf16 convert (x, Wqkv, Wo) + vT halo zero ----------------
#define XQ 1048576
#define WQKVQ 786432
#define WOQ 262144
#define CVTQ (XQ + WQKVQ + WOQ)      // 2,097,152 quads
__global__ __launch_bounds__(256) void cvt3_kernel(
    const float* __restrict__ x, const float* __restrict__ wqkv, const float* __restrict__ wo,
    unsigned short* __restrict__ xb, unsigned short* __restrict__ wqkvb, unsigned short* __restrict__ wob,
    unsigned short* __restrict__ vTp) {
  int i = blockIdx.x * blockDim.x + threadIdx.x;
  if (i < CVTQ) {
    const float* s; unsigned short* d; int off;
    if (i < XQ)               { s = x;    d = xb;    off = i; }
    else if (i < XQ + WQKVQ)  { s = wqkv; d = wqkvb; off = i - XQ; }
    else                      { s = wo;   d = wob;   off = i - XQ - WQKVQ; }
    float4 f = reinterpret_cast<const float4*>(s)[off];
    ushort4 o;
    o.x = f2bf(f.x); o.y = f2bf(f.y); o.z = f2bf(f.z); o.w = f2bf(f.w);
    reinterpret_cast<ushort4*>(d)[off] = o;
  } else {
    int j = i - CVTQ;                      // 0..147455
    int row = j / 72, p = j % 72;          // row = bh*64+d
    int off = row * 584 + (p < 32 ? p : 544 + (p - 32));  // left 128 u16 / right 160 u16
    reinterpret_cast<ushort4*>(vTp)[off] = (ushort4){0, 0, 0, 0};
  }
}

// ---------------- QKV GEMM: 256x192 tile, BK=64, 4-phase interleaved schedule ----------------
// nb = head (0..15); grid 256 = 16mb x 16nb, bid%8 = nb%8 -> head home XCD matches attn.
// 512 thr = 8 waves (4M x 2N), per-wave 64x96, acc 4x6.
// Per K-tile: 4 phases {ds_read subtile; issue stage units; s_barrier; lgkmcnt(0);
// setprio(1) 12 MFMA setprio(0); s_barrier}. Stage units of tile T+1 spread over
// P0-P2 ({3,2,2}/wave); single vmcnt(0) at P3 (drained loads are >=1 phase old).
// LDS rows 128B: XOR-seg swizzle (T2) both-sides: pre-swizzled global src + swizzled read.
__global__ __launch_bounds__(512, 2) void gemm_qkv(
    const unsigned short* __restrict__ A, const unsigned short* __restrict__ Bm,
    const float* __restrict__ bias, const int* __restrict__ pm,
    unsigned short* __restrict__ qo, unsigned short* __restrict__ ko,
    unsigned short* __restrict__ vTp)
{
  // 2 slabs x (A 256x64 + B 192x64) u16 = 114,688 B; epilogue C [256][200] u16 aliased
  __shared__ __align__(16) unsigned short smem[57344];
  const int t = threadIdx.x, wave = t >> 6, lane = t & 63;
  const int m16 = lane & 15, q4 = lane >> 4;
  const int wm = wave >> 1, wn = wave & 1;          // 4x2 waves, each 64 rows x 96 cols
  const int bid = blockIdx.x;
  const int mb = bid >> 4, nb = bid & 15;           // bid%8 == nb%8 -> XCD affinity
  // staging: 56 units of 8 rows x 64k (1 KB); wave w owns units w*7..w*7+6
  const int lrow = lane >> 3;                        // row within unit
  const int lsegsw = ((lane & 7) ^ lrow) * 8;        // pre-swizzled global seg (u16 off)
  const unsigned short* gsrc[7];
#pragma unroll
  for (int j = 0; j < 7; j++) {
    int u = wave * 7 + j;
    gsrc[j] = (u < 32 ? A  + (size_t)(mb * 256 + u * 8 + lrow) * KDIM
                      : Bm + (size_t)(nb * 192 + (u - 32) * 8 + lrow) * KDIM)
              + lsegsw;
  }
  const int rsw = (m16 & 7) * 8;                     // read-side swizzle (u16 XOR)

  f32x4 acc[4][6];
#pragma unroll
  for (int i_ = 0; i_ < 4; i_++)
#pragma unroll
    for (int j_ = 0; j_ < 6; j_++) acc[i_][j_] = (f32x4){0.f, 0.f, 0.f, 0.f};

  auto LDA = [&](short8* af, const unsigned short* As, int h) {
#pragma unroll
    for (int mt = 0; mt < 4; mt++)
      af[mt] = *reinterpret_cast<const short8*>(
          &As[(wm * 64 + mt * 16 + m16) * 64 + (((h * 4 + q4) * 8) ^ rsw)]);
  };
  auto LDB3 = [&](short8* bf, const unsigned short* Bs, int h, int n0) {
#pragma unroll
    for (int nt = 0; nt < 3; nt++)
      bf[nt] = *reinterpret_cast<const short8*>(
          &Bs[(wn * 96 + (n0 + nt) * 16 + m16) * 64 + (((h * 4 + q4) * 8) ^ rsw)]);
  };
  auto MM3 = [&](short8* af, short8* bf, int n0) {
#pragma unroll
    for (int mt = 0; mt < 4; mt++)
#pragma unroll
      for (int nt = 0; nt < 3; nt++)
        acc[mt][n0 + nt] =
            __builtin_amdgcn_mfma_f32_16x16x32_bf16(af[mt], bf[nt], acc[mt][n0 + nt], 0, 0, 0);
  };

  // prologue: tile 0 -> slab 0
#pragma unroll
  for (int j = 0; j < 7; j++)
    gload_lds16(gsrc[j], smem + (wave * 7 + j) * 512);
  asm volatile("s_waitcnt vmcnt(0)" ::: "memory");
  __builtin_amdgcn_s_barrier();
  __builtin_amdgcn_sched_barrier(0);

  for (int T = 0; T < 16; ++T) {
    const int c = T & 1;
    const unsigned short* As = smem + c * 28672;
    const unsigned short* Bs = As + 16384;
    unsigned short* nslab = smem + (c ^ 1) * 28672;
    const int nkt = (T + 1) * 64;
    const bool st = (T < 15);
    short8 af[4], bf[3];

    // ---- P0: af[h0] + bf0-2[h0]; stage units 0-2; MFMA h0 x nt0-2 ----
    LDA(af, As, 0);
    LDB3(bf, Bs, 0, 0);
    if (st) {
#pragma unroll
      for (int j = 0; j < 3; j++)
        gload_lds16(gsrc[j] + nkt, nslab + (wave * 7 + j) * 512);
    }
    __builtin_amdgcn_sched_barrier(0);
    __builtin_amdgcn_s_barrier();
    asm volatile("s_waitcnt lgkmcnt(0)" ::: "memory");
    __builtin_amdgcn_sched_barrier(0);
    __builtin_amdgcn_s_setprio(1);
    MM3(af, bf, 0);
    __builtin_amdgcn_s_setprio(0);
    __builtin_amdgcn_sched_barrier(0);
    __builtin_amdgcn_s_barrier();
    __builtin_amdgcn_sched_barrier(0);

    // ---- P1: bf3-5[h0]; stage units 3-4; MFMA h0 x nt3-5 (af live from P0) ----
    LDB3(bf, Bs, 0, 3);
    if (st) {
#pragma unroll
      for (int j = 3; j < 5; j++)
        gload_lds16(gsrc[j] + nkt, nslab + (wave * 7 + j) * 512);
    }
    __builtin_amdgcn_sched_barrier(0);
    __builtin_amdgcn_s_barrier();
    asm volatile("s_waitcnt lgkmcnt(0)" ::: "memory");
    __builtin_amdgcn_sched_barrier(0);
    __builtin_amdgcn_s_setprio(1);
    MM3(af, bf, 3);
    __builtin_amdgcn_s_setprio(0);
    __builtin_amdgcn_sched_barrier(0);
    __builtin_amdgcn_s_barrier();
    __builtin_amdgcn_sched_barrier(0);

    // ---- P2: af[h1] + bf0-2[h1]; stage units 5-6; MFMA h1 x nt0-2 ----
    LDA(af, As, 1);
    LDB3(bf, Bs, 1, 0);
    if (st) {
#pragma unroll
      for (int j = 5; j < 7; j++)
        gload_lds16(gsrc[j] + nkt, nslab + (wave * 7 + j) * 512);
    }
    __builtin_amdgcn_sched_barrier(0);
    __builtin_amdgcn_s_barrier();
    asm volatile("s_waitcnt lgkmcnt(0)" ::: "memory");
    __builtin_amdgcn_sched_barrier(0);
    __builtin_amdgcn_s_setprio(1);
    MM3(af, bf, 0);
    __builtin_amdgcn_s_setprio(0);
    __builtin_amdgcn_sched_barrier(0);
    __builtin_amdgcn_s_barrier();
    __builtin_amdgcn_sched_barrier(0);

    // ---- P3: bf3-5[h1]; vmcnt(0) (tile T+1 units all >=1 phase old); MFMA h1 x nt3-5 ----
    LDB3(bf, Bs, 1, 3);
    asm volatile("s_waitcnt vmcnt(0)" ::: "memory");
    __builtin_amdgcn_sched_barrier(0);
    __builtin_amdgcn_s_barrier();
    asm volatile("s_waitcnt lgkmcnt(0)" ::: "memory");
    __builtin_amdgcn_sched_barrier(0);
    __builtin_amdgcn_s_setprio(1);
    MM3(af, bf, 3);
    __builtin_amdgcn_s_setprio(0);
    __builtin_amdgcn_sched_barrier(0);
    __builtin_amdgcn_s_barrier();
    __builtin_amdgcn_sched_barrier(0);
  }

  // ---- epilogue: C via LDS [256][CLP2], then q/k/vT writeout ----
  float pmv[4][4];
#pragma unroll
  for (int mt = 0; mt < 4; mt++)
#pragma unroll
    for (int reg = 0; reg < 4; reg++) {
      int row = mb * 256 + wm * 64 + mt * 16 + q4 * 4 + reg;
      pmv[mt][reg] = (pm[row] != 0) ? 0.0f : 1.0f;
    }
#pragma unroll
  for (int nt = 0; nt < 6; nt++) {
    int cloc = wn * 96 + nt * 16 + m16;
    float bv = bias[nb * 192 + cloc];
#pragma unroll
    for (int mt = 0; mt < 4; mt++) {
#pragma unroll
      for (int reg = 0; reg < 4; reg++) {
        int rloc = wm * 64 + mt * 16 + q4 * 4 + reg;
        smem[rloc * CLP2 + cloc] = f2bf((acc[mt][nt][reg] + bv) * pmv[mt][reg]);
      }
    }
  }
  __syncthreads();
  const int s0 = mb * 256;                 // 256-row tiles never cross the 2048 batch boundary
  const int bh = (s0 >> 11) * 16 + nb, s0l = s0 & 2047;
  // q/k writeout: thread -> (row r of 256, 32-col half): 64 B q + 64 B k
  {
    int r = t >> 1, half = t & 1;
    const unsigned short* sq = &smem[r * CLP2 + half * 32];
    unsigned short* dq = qo + ((size_t)(bh * 2048 + s0l + r)) * 64 + half * 32;
#pragma unroll
    for (int j = 0; j < 4; j++)
      *reinterpret_cast<short8*>(dq + j * 8) = *reinterpret_cast<const short8*>(sq + j * 8);
    const unsigned short* sk = &smem[r * CLP2 + 64 + half * 32];
    unsigned short* dk = ko + ((size_t)(bh * 2048 + s0l + r)) * 64 + half * 32;
#pragma unroll
    for (int j = 0; j < 4; j++)
      *reinterpret_cast<short8*>(dk + j * 8) = *reinterpret_cast<const short8*>(sk + j * 8);
  }
  // vT writeout: thread -> (d = t&63, 32-row octant): 64 B contiguous in s
  {
    int d = t & 63, oct = t >> 6;
    unsigned short* dst = vTp + (size_t)(bh * 64 + d) * SP + 128 + s0l + oct * 32;
#pragma unroll
    for (int j8 = 0; j8 < 4; j8++) {
      short8 tmp;
#pragma unroll
      for (int jj = 0; jj < 8; jj++)
        tmp[jj] = (short)smem[(oct * 32 + j8 * 8 + jj) * CLP2 + 128 + d];
      *reinterpret_cast<short8*>(dst + j8 * 8) = tmp;
    }
  }
}

// ---------------- output projection: 64x128 tile, BK=64, 2-phase dbuf ----------------
// 512 blocks = 2/CU.
__global__ __launch_bounds__(256) void gemm_out(
    const unsigned short* __restrict__ A, const unsigned short* __restrict__ Bm,
    const float* __restrict__ bias, float* __restrict__ out)
{
  // staging: 2 bufs x (As 64x32 + Bs 128x32)/half... 2 x 12288 u16 = 49,152 B
  // epilogue: Cldf [64][132] f32 = 33,792 B aliased over staging
  __shared__ __align__(16) unsigned char smemraw[49152];
  float* Cldf = (float*)smemraw;
  const int t = threadIdx.x, wave = t >> 6, lane = t & 63;
  const int m16 = lane & 15, q4 = lane >> 4;
  const int wm = wave >> 1, wn = wave & 1;                // 2x2 waves: 32 rows x 64 cols each
  const int flat = blockIdx.y * 8 + blockIdx.x;
  const int xcd = flat & 7, bi = flat >> 3;
  const int mb = xcd * 8 + (bi & 7);                      // per XCD: 8 mb x 8 nb
  const int nb = bi >> 3;
  const int srow = lane >> 2, scol = (lane & 3) << 3;
  const unsigned short* pA  = A + (size_t)(mb * 64 + wave * 16 + srow) * KDIM + scol;
  const unsigned short* pB0 = Bm + (size_t)(nb * 128 + wave * 32 + srow) * KDIM + scol;
  const unsigned short* pB1 = pB0 + 16 * KDIM;
  f32x4 acc[2][4];
#pragma unroll
  for (int i_ = 0; i_ < 2; i_++)
#pragma unroll
    for (int j_ = 0; j_ < 4; j_++) acc[i_][j_] = (f32x4){0.f, 0.f, 0.f, 0.f};

  auto stage = [&](int buf, int kt) {
    unsigned short* As = (unsigned short*)smemraw + buf * 12288;
    unsigned short* Bs = As + 4096;
#pragma unroll
    for (int h = 0; h < 2; h++) {
      gload_lds16(pA + kt + h * 32,  As + h * 2048 + (wave * 16) * 32);
      gload_lds16(pB0 + kt + h * 32, Bs + h * 4096 + (wave * 32) * 32);
      gload_lds16(pB1 + kt + h * 32, Bs + h * 4096 + (wave * 32 + 16) * 32);
    }
  };

  stage(0, 0);
  __syncthreads();
  int cur = 0;
  for (int kt = 0; kt < KDIM; kt += 64) {
    if (kt + 64 < KDIM) stage(cur ^ 1, kt + 64);
    const unsigned short* As = (const unsigned short*)smemraw + cur * 12288;
    const unsigned short* Bs = As + 4096;
#pragma unroll
    for (int h = 0; h < 2; h++) {
      short8 af[2], bf[4];
#pragma unroll
      for (int mt = 0; mt < 2; mt++)
        af[mt] = *reinterpret_cast<const short8*>(&As[h * 2048 + (wm * 32 + mt * 16 + m16) * 32 + q4 * 8]);
#pragma unroll
      for (int nt = 0; nt < 4; nt++)
        bf[nt] = *reinterpret_cast<const short8*>(&Bs[h * 4096 + (wn * 64 + nt * 16 + m16) * 32 + q4 * 8]);
#pragma unroll
      for (int mt = 0; mt < 2; mt++)
#pragma unroll
        for (int nt = 0; nt < 4; nt++)
          acc[mt][nt] = __builtin_amdgcn_mfma_f32_16x16x32_bf16(af[mt], bf[nt], acc[mt][nt], 0, 0, 0);
    }
    __syncthreads();
    cur ^= 1;
  }

#pragma unroll
  for (int nt = 0; nt < 4; nt++) {
    int cloc = wn * 64 + nt * 16 + m16;
    float bv = bias[nb * 128 + cloc];
#pragma unroll
    for (int mt = 0; mt < 2; mt++) {
#pragma unroll
      for (int reg = 0; reg < 4; reg++) {
        int rloc = wm * 32 + mt * 16 + q4 * 4 + reg;
        Cldf[rloc * 132 + cloc] = acc[mt][nt][reg] + bv;
      }
    }
  }
  __syncthreads();
  {
    int r = t >> 2, seg = t & 3;   // 64 rows x 4 segments of 32 floats (128 B)
    float* dst = out + (size_t)(mb * 64 + r) * EMBED + nb * 128 + seg * 32;
    const float* srcl = &Cldf[r * 132 + seg * 32];
#pragma unroll
    for (int j = 0; j < 8; j++)
      *reinterpret_cast<float4*>(dst + j * 4) = *reinterpret_cast<const float4*>(srcl + j * 4);
  }
}

// ---------------- banded attention v3: bulk LDS staging, branch-free ----------------
__global__ __launch_bounds__(256, 2) void attn_kernel(
    const unsigned short* __restrict__ q, const unsigned short* __restrict__ k,
    const unsigned short* __restrict__ vTp, unsigned short* __restrict__ vals)
{
  __shared__ __align__(16) unsigned short smem[40960];   // 81,920 B
  unsigned short* Ks = smem;            // [320][64] u16 (40,960 B)
  unsigned short* Vs = smem + 20480;    // [64][320] u16 (40,960 B)
  unsigned short* Pld = smem;           // alias over Ks after QK phase: [4][16][296]

  const int bid = blockIdx.x;
  const int bh = bid & 31, qg = bid >> 5;                // bh-fastest: XCD-local K/V
  const int lane = threadIdx.x & 63, wave = threadIdx.x >> 6;
  const int i0b = qg * 64;
  const int i0 = i0b + wave * 16;
  const int m16 = lane & 15, q4 = lane >> 4;

  // ---- stage K window: 40 KB = 40 wave-issues of 1 KB (10 per wave) ----
  const unsigned short* kbase = k + (size_t)bh * 2048 * 64;
#pragma unroll
  for (int n = 0; n < 10; n++) {
    int idx = (n * 4 + wave) * 64 + lane;      // 0..2559
    int krow = idx >> 3, seg = idx & 7;
    int grow = i0b - 128 + krow;
    grow = grow < 0 ? 0 : (grow > 2047 ? 2047 : grow);
    int lseg = seg ^ (krow & 7);               // store swizzled within 128B row
    gload_lds16(kbase + (size_t)grow * 64 + lseg * 8, Ks + (n * 4 + wave) * 512);
  }
  // ---- stage V^T window: 40 KB, rows of 320 u16 (40 segs of 16B) ----
  const unsigned short* vbase = vTp + (size_t)bh * 64 * SP + i0b;  // col(i0b) == key i0b-128
#pragma unroll
  for (int n = 0; n < 10; n++) {
    int idx = (n * 4 + wave) * 64 + lane;      // 0..2559
    int vrow = idx / 40, rem = idx % 40;
    int l = (rem & ~7) | ((rem & 7) ^ (vrow & 7));
    gload_lds16(vbase + (size_t)vrow * SP + l * 8, Vs + (n * 4 + wave) * 512);
  }

  // q fragments (direct, tiny)
  const unsigned short* qb = q + ((size_t)(bh * 2048 + i0 + m16)) * 64 + q4 * 8;
  short8 aq0 = *reinterpret_cast<const short8*>(qb);
  short8 aq1 = *reinterpret_cast<const short8*>(qb + 32);

  __syncthreads();

  // ---- QK^T + streaming exp, P packed in registers ----
  float sum[4] = {0.f, 0.f, 0.f, 0.f};
  uint32_t pP[18][2];
#pragma unroll
  for (int ct = 0; ct < 18; ct++) {
    int r = (wave + ct) * 16 + m16;            // LDS key row (may run past 320: finite data, masked)
    int js = i0b - 128 + r;                    // global key index
    const unsigned short* kr = Ks + r * 64;
    short8 b0 = *reinterpret_cast<const short8*>(kr + ((q4 ^ (r & 7)) * 8));
    short8 b1 = *reinterpret_cast<const short8*>(kr + (((q4 + 4) ^ (r & 7)) * 8));
    f32x4 a = {0.f, 0.f, 0.f, 0.f};
    a = __builtin_amdgcn_mfma_f32_16x16x32_bf16(aq0, b0, a, 0, 0, 0);
    a = __builtin_amdgcn_mfma_f32_16x16x32_bf16(aq1, b1, a, 0, 0, 0);
    unsigned short pe[4];
#pragma unroll
    for (int reg = 0; reg < 4; reg++) {
      int i = i0 + q4 * 4 + reg;
      bool valid = (js >= 0) && (js < 2048) && (js >= i - 128) && (js <= i + 128);
      float e = valid ? __expf(a[reg] * 0.125f) : 0.0f;
      sum[reg] += e;
      pe[reg] = f2bf(e);
    }
    pP[ct][0] = (uint32_t)pe[0] | ((uint32_t)pe[1] << 16);
    pP[ct][1] = (uint32_t)pe[2] | ((uint32_t)pe[3] << 16);
  }
  float rden[4];
#pragma unroll
  for (int reg = 0; reg < 4; reg++) {
    float s = sum[reg];
    s += __shfl_xor(s, 1);
    s += __shfl_xor(s, 2);
    s += __shfl_xor(s, 4);
    s += __shfl_xor(s, 8);
    rden[reg] = 1.0f / s;
  }

  __syncthreads();   // all Ks reads done; Pld may now overwrite Ks

  unsigned short* Pw = Pld + wave * 16 * 296;
#pragma unroll
  for (int ct = 0; ct < 18; ct++) {
    Pw[(q4 * 4 + 0) * 296 + ct * 16 + m16] = (unsigned short)(pP[ct][0] & 0xFFFF);
    Pw[(q4 * 4 + 1) * 296 + ct * 16 + m16] = (unsigned short)(pP[ct][0] >> 16);
    Pw[(q4 * 4 + 2) * 296 + ct * 16 + m16] = (unsigned short)(pP[ct][1] & 0xFFFF);
    Pw[(q4 * 4 + 3) * 296 + ct * 16 + m16] = (unsigned short)(pP[ct][1] >> 16);
  }
  // own-wave LDS ordering handled by lgkmcnt; no block barrier needed
  short8 ap[9];
#pragma unroll
  for (int kc = 0; kc < 9; kc++)
    ap[kc] = *reinterpret_cast<const short8*>(&Pw[m16 * 296 + kc * 32 + q4 * 8]);

  const int b = bh >> 4, h = bh & 15;
#pragma unroll
  for (int dt = 0; dt < 4; dt++) {
    int vrow = dt * 16 + m16;
    const unsigned short* vr = Vs + vrow * 320;
    f32x4 av = {0.f, 0.f, 0.f, 0.f};
#pragma unroll
    for (int kc = 0; kc < 9; kc++) {
      int jseg = kc * 4 + wave * 2 + q4;       // logical 16B seg within V^T row
      if (jseg > 39) jseg = 39;                // clamp: clamped segs have P==0
      int sseg = (jseg & ~7) | ((jseg & 7) ^ (vrow & 7));
      short8 bv = *reinterpret_cast<const short8*>(vr + sseg * 8);
      av = __builtin_amdgcn_mfma_f32_16x16x32_bf16(ap[kc], bv, av, 0, 0, 0);
    }
#pragma unroll
    for (int reg = 0; reg < 4; reg++)
      Pw[(q4 * 4 + reg) * 296 + dt * 16 + m16] = f2bf(av[reg] * rden[reg]);
  }
  // coalesced O writeout: 4 lanes x 32B per row -> full 128B lines
  {
    int srow = lane >> 2, seg = lane & 3;
    unsigned short* dst = vals + ((size_t)(b * 2048 + i0 + srow)) * 1024 + h * 64 + seg * 16;
    const unsigned short* srcl = &Pw[srow * 296 + seg * 16];
    *reinterpret_cast<short8*>(dst)     = *reinterpret_cast<const short8*>(srcl);
    *reinterpret_cast<short8*>(dst + 8) = *reinterpret_cast<const short8*>(srcl + 8);
  }
}

extern "C" void kernel_launch(void* const* d_in, const int* in_sizes, int n_in,
                              void* d_out, int out_size, void* d_ws, size_t ws_size,
                              hipStream_t stream) {
  const float* x    = (const float*)d_in[0];
  const int*   pm   = (const int*)d_in[1];
  const float* Wqkv = (const float*)d_in[2];
  const float* bqkv = (const float*)d_in[3];
  const float* Wo   = (const float*)d_in[4];
  const float* bo   = (const float*)d_in[5];
  float* out = (float*)d_out;
  char* ws = (char*)d_ws;

  unsigned short* xb    = (unsigned short*)(ws);                 //  8,388,608
  unsigned short* vals  = (unsigned short*)(ws);                 //  reuse (xb dead after gemm_qkv)
  unsigned short* Wqkvb = (unsigned short*)(ws +  8388608);      //  6,291,456
  unsigned short* Wob   = (unsigned short*)(ws + 14680064);      //  2,097,152
  unsigned short* qbuf  = (unsigned short*)(ws + 16777216);      //  8,388,608
  unsigned short* kbuf  = (unsigned short*)(ws + 25165824);      //  8,388,608
  unsigned short* vTp   = (unsigned short*)(ws + 33554432);      //  9,568,256 (ends 43,122,688)

  cvt3_kernel<<<8768, 256, 0, stream>>>(x, Wqkv, Wo, xb, Wqkvb, Wob, vTp);
  gemm_qkv<<<256, 512, 0, stream>>>(xb, Wqkvb, bqkv, pm, qbuf, kbuf, vTp);
  attn_kernel<<<1024, 256, 0, stream>>>(qbuf, kbuf, vTp, vals);
  gemm_out<<<dim3(8, 64), 256, 0, stream>>>(vals, Wob, bo, out);
}

// Round 3
// 159.108 us; speedup vs baseline: 1.0550x; 1.0123x over previous
//
#include <hip/hip_runtime.h>
#include <stdint.h>

#define S_LEN 2048
#define EMBED 1024
#define HEADS 16
#define HD 64
#define M_ROWS 4096      // B*S
#define N_QKV 3072
#define KDIM 1024
#define SP 2336          // padded vT row length: 128 + 2048 + 160
#define CLP2 200         // qkv C-tile LDS col stride (u16)

typedef __attribute__((ext_vector_type(8))) short short8;
typedef __attribute__((ext_vector_type(4))) float f32x4;

__device__ __forceinline__ unsigned short f2bf(float f) {
  union { float f; uint32_t u; } c; c.f = f;
  uint32_t u = c.u;
  u += 0x7fffu + ((u >> 16) & 1u);  // round-to-nearest-even
  return (unsigned short)(u >> 16);
}

// async global->LDS, 16B per lane; lds base must be wave-uniform (HW adds lane*16)
__device__ __forceinline__ void gload_lds16(const unsigned short* g, unsigned short* l) {
  __builtin_amdgcn_global_load_lds(
      (const __attribute__((address_space(1))) void*)g,
      (__attribute__((address_space(3))) void*)l, 16, 0, 0);
}

// ---------------- fused fp32->bf16 convert (x, Wqkv, Wo) + vT halo zero ----------------
#define XQ 1048576
#define WQKVQ 786432
#define WOQ 262144
#define CVTQ (XQ + WQKVQ + WOQ)      // 2,097,152 quads
__global__ __launch_bounds__(256) void cvt3_kernel(
    const float* __restrict__ x, const float* __restrict__ wqkv, const float* __restrict__ wo,
    unsigned short* __restrict__ xb, unsigned short* __restrict__ wqkvb, unsigned short* __restrict__ wob,
    unsigned short* __restrict__ vTp) {
  int i = blockIdx.x * blockDim.x + threadIdx.x;
  if (i < CVTQ) {
    const float* s; unsigned short* d; int off;
    if (i < XQ)               { s = x;    d = xb;    off = i; }
    else if (i < XQ + WQKVQ)  { s = wqkv; d = wqkvb; off = i - XQ; }
    else                      { s = wo;   d = wob;   off = i - XQ - WQKVQ; }
    float4 f = reinterpret_cast<const float4*>(s)[off];
    ushort4 o;
    o.x = f2bf(f.x); o.y = f2bf(f.y); o.z = f2bf(f.z); o.w = f2bf(f.w);
    reinterpret_cast<ushort4*>(d)[off] = o;
  } else {
    int j = i - CVTQ;                      // 0..147455
    int row = j / 72, p = j % 72;          // row = bh*64+d
    int off = row * 584 + (p < 32 ? p : 544 + (p - 32));  // left 128 u16 / right 160 u16
    reinterpret_cast<ushort4*>(vTp)[off] = (ushort4){0, 0, 0, 0};
  }
}

// ---------------- QKV GEMM: 256x192 tile, BK=64, 4-phase + COUNTED vmcnt (T4) ----------------
// nb = head (0..15); grid 256 = 16mb x 16nb, bid%8 = nb%8 -> head home XCD matches attn.
// 512 thr = 8 waves (4M x 2N), per-wave 64x96, acc 4x6.
// T4 discipline (m218): NO vmcnt(0) in the main loop. At P0 of tile T: issue 3 fresh
// stage units, then vmcnt(3) -> in-order retire guarantees ALL 7 units of the slab
// about to be read have landed, while fresh loads stay in flight. barrier AFTER the
// vmcnt and BEFORE the ds_reads makes the guarantee block-wide.
__global__ __launch_bounds__(512, 2) void gemm_qkv(
    const unsigned short* __restrict__ A, const unsigned short* __restrict__ Bm,
    const float* __restrict__ bias, const int* __restrict__ pm,
    unsigned short* __restrict__ qo, unsigned short* __restrict__ ko,
    unsigned short* __restrict__ vTp)
{
  // 2 slabs x (A 256x64 + B 192x64) u16 = 114,688 B; epilogue C [256][200] u16 aliased
  __shared__ __align__(16) unsigned short smem[57344];
  const int t = threadIdx.x, wave = t >> 6, lane = t & 63;
  const int m16 = lane & 15, q4 = lane >> 4;
  const int wm = wave >> 1, wn = wave & 1;          // 4x2 waves, each 64 rows x 96 cols
  const int bid = blockIdx.x;
  const int mb = bid >> 4, nb = bid & 15;           // bid%8 == nb%8 -> XCD affinity
  // staging: 56 units of 8 rows x 64k (1 KB); wave w owns units w*7..w*7+6
  const int lrow = lane >> 3;                        // row within unit
  const int lsegsw = ((lane & 7) ^ lrow) * 8;        // pre-swizzled global seg (u16 off)
  const unsigned short* gsrc[7];
#pragma unroll
  for (int j = 0; j < 7; j++) {
    int u = wave * 7 + j;
    gsrc[j] = (u < 32 ? A  + (size_t)(mb * 256 + u * 8 + lrow) * KDIM
                      : Bm + (size_t)(nb * 192 + (u - 32) * 8 + lrow) * KDIM)
              + lsegsw;
  }
  const int rsw = (m16 & 7) * 8;                     // read-side swizzle (u16 XOR)

  f32x4 acc[4][6];
#pragma unroll
  for (int i_ = 0; i_ < 4; i_++)
#pragma unroll
    for (int j_ = 0; j_ < 6; j_++) acc[i_][j_] = (f32x4){0.f, 0.f, 0.f, 0.f};

  auto LDA = [&](short8* af, const unsigned short* As, int h) {
#pragma unroll
    for (int mt = 0; mt < 4; mt++)
      af[mt] = *reinterpret_cast<const short8*>(
          &As[(wm * 64 + mt * 16 + m16) * 64 + (((h * 4 + q4) * 8) ^ rsw)]);
  };
  auto LDB3 = [&](short8* bf, const unsigned short* Bs, int h, int n0) {
#pragma unroll
    for (int nt = 0; nt < 3; nt++)
      bf[nt] = *reinterpret_cast<const short8*>(
          &Bs[(wn * 96 + (n0 + nt) * 16 + m16) * 64 + (((h * 4 + q4) * 8) ^ rsw)]);
  };
  auto MM3 = [&](short8* af, short8* bf, int n0) {
#pragma unroll
    for (int mt = 0; mt < 4; mt++)
#pragma unroll
      for (int nt = 0; nt < 3; nt++)
        acc[mt][n0 + nt] =
            __builtin_amdgcn_mfma_f32_16x16x32_bf16(af[mt], bf[nt], acc[mt][n0 + nt], 0, 0, 0);
  };

  // prologue: issue tile 0 -> slab 0 (no wait here; T=0 P0's vmcnt(3) is the guarantee)
#pragma unroll
  for (int j = 0; j < 7; j++)
    gload_lds16(gsrc[j], smem + (wave * 7 + j) * 512);
  __builtin_amdgcn_sched_barrier(0);

  for (int T = 0; T < 16; ++T) {
    const int c = T & 1;
    const unsigned short* As = smem + c * 28672;
    const unsigned short* Bs = As + 16384;
    unsigned short* nslab = smem + (c ^ 1) * 28672;
    const int nkt = (T + 1) * 64;
    const bool st = (T < 15);
    short8 af[4], bf[3];

    // ---- P0: stage 0-2; COUNTED vmcnt; barrier; ds_read af[h0]+bf[h0,0-2]; MFMA ----
    if (st) {
#pragma unroll
      for (int j = 0; j < 3; j++)
        gload_lds16(gsrc[j] + nkt, nslab + (wave * 7 + j) * 512);
    }
    __builtin_amdgcn_sched_barrier(0);
    if (st) asm volatile("s_waitcnt vmcnt(3)" ::: "memory");
    else    asm volatile("s_waitcnt vmcnt(0)" ::: "memory");
    __builtin_amdgcn_sched_barrier(0);
    __builtin_amdgcn_s_barrier();
    __builtin_amdgcn_sched_barrier(0);
    LDA(af, As, 0);
    LDB3(bf, Bs, 0, 0);
    asm volatile("s_waitcnt lgkmcnt(0)" ::: "memory");
    __builtin_amdgcn_sched_barrier(0);
    __builtin_amdgcn_s_setprio(1);
    MM3(af, bf, 0);
    __builtin_amdgcn_s_setprio(0);
    __builtin_amdgcn_sched_barrier(0);
    __builtin_amdgcn_s_barrier();
    __builtin_amdgcn_sched_barrier(0);

    // ---- P1: ds_read bf[h0,3-5]; stage 3-4; barrier; MFMA (af live from P0) ----
    LDB3(bf, Bs, 0, 3);
    if (st) {
#pragma unroll
      for (int j = 3; j < 5; j++)
        gload_lds16(gsrc[j] + nkt, nslab + (wave * 7 + j) * 512);
    }
    __builtin_amdgcn_sched_barrier(0);
    __builtin_amdgcn_s_barrier();
    asm volatile("s_waitcnt lgkmcnt(0)" ::: "memory");
    __builtin_amdgcn_sched_barrier(0);
    __builtin_amdgcn_s_setprio(1);
    MM3(af, bf, 3);
    __builtin_amdgcn_s_setprio(0);
    __builtin_amdgcn_sched_barrier(0);
    __builtin_amdgcn_s_barrier();
    __builtin_amdgcn_sched_barrier(0);

    // ---- P2: ds_read af[h1]+bf[h1,0-2]; stage 5-6; barrier; MFMA ----
    LDA(af, As, 1);
    LDB3(bf, Bs, 1, 0);
    if (st) {
#pragma unroll
      for (int j = 5; j < 7; j++)
        gload_lds16(gsrc[j] + nkt, nslab + (wave * 7 + j) * 512);
    }
    __builtin_amdgcn_sched_barrier(0);
    __builtin_amdgcn_s_barrier();
    asm volatile("s_waitcnt lgkmcnt(0)" ::: "memory");
    __builtin_amdgcn_sched_barrier(0);
    __builtin_amdgcn_s_setprio(1);
    MM3(af, bf, 0);
    __builtin_amdgcn_s_setprio(0);
    __builtin_amdgcn_sched_barrier(0);
    __builtin_amdgcn_s_barrier();
    __builtin_amdgcn_sched_barrier(0);

    // ---- P3: ds_read bf[h1,3-5]; barrier; MFMA (NO vmcnt here - T4) ----
    LDB3(bf, Bs, 1, 3);
    __builtin_amdgcn_sched_barrier(0);
    __builtin_amdgcn_s_barrier();
    asm volatile("s_waitcnt lgkmcnt(0)" ::: "memory");
    __builtin_amdgcn_sched_barrier(0);
    __builtin_amdgcn_s_setprio(1);
    MM3(af, bf, 3);
    __builtin_amdgcn_s_setprio(0);
    __builtin_amdgcn_sched_barrier(0);
    __builtin_amdgcn_s_barrier();
    __builtin_amdgcn_sched_barrier(0);
  }

  // ---- epilogue: C via LDS [256][CLP2], then q/k/vT writeout ----
  float pmv[4][4];
#pragma unroll
  for (int mt = 0; mt < 4; mt++)
#pragma unroll
    for (int reg = 0; reg < 4; reg++) {
      int row = mb * 256 + wm * 64 + mt * 16 + q4 * 4 + reg;
      pmv[mt][reg] = (pm[row] != 0) ? 0.0f : 1.0f;
    }
#pragma unroll
  for (int nt = 0; nt < 6; nt++) {
    int cloc = wn * 96 + nt * 16 + m16;
    float bv = bias[nb * 192 + cloc];
#pragma unroll
    for (int mt = 0; mt < 4; mt++) {
#pragma unroll
      for (int reg = 0; reg < 4; reg++) {
        int rloc = wm * 64 + mt * 16 + q4 * 4 + reg;
        smem[rloc * CLP2 + cloc] = f2bf((acc[mt][nt][reg] + bv) * pmv[mt][reg]);
      }
    }
  }
  __syncthreads();
  const int s0 = mb * 256;                 // 256-row tiles never cross the 2048 batch boundary
  const int bh = (s0 >> 11) * 16 + nb, s0l = s0 & 2047;
  // q/k writeout: thread -> (row r of 256, 32-col half): 64 B q + 64 B k
  {
    int r = t >> 1, half = t & 1;
    const unsigned short* sq = &smem[r * CLP2 + half * 32];
    unsigned short* dq = qo + ((size_t)(bh * 2048 + s0l + r)) * 64 + half * 32;
#pragma unroll
    for (int j = 0; j < 4; j++)
      *reinterpret_cast<short8*>(dq + j * 8) = *reinterpret_cast<const short8*>(sq + j * 8);
    const unsigned short* sk = &smem[r * CLP2 + 64 + half * 32];
    unsigned short* dk = ko + ((size_t)(bh * 2048 + s0l + r)) * 64 + half * 32;
#pragma unroll
    for (int j = 0; j < 4; j++)
      *reinterpret_cast<short8*>(dk + j * 8) = *reinterpret_cast<const short8*>(sk + j * 8);
  }
  // vT writeout: thread -> (d = t&63, 32-row octant): 64 B contiguous in s
  {
    int d = t & 63, oct = t >> 6;
    unsigned short* dst = vTp + (size_t)(bh * 64 + d) * SP + 128 + s0l + oct * 32;
#pragma unroll
    for (int j8 = 0; j8 < 4; j8++) {
      short8 tmp;
#pragma unroll
      for (int jj = 0; jj < 8; jj++)
        tmp[jj] = (short)smem[(oct * 32 + j8 * 8 + jj) * CLP2 + 128 + d];
      *reinterpret_cast<short8*>(dst + j8 * 8) = tmp;
    }
  }
}

// ---------------- output projection: 64x128 tile, BK=64, dbuf + COUNTED vmcnt ----------------
// 512 blocks = 2/CU. Raw s_barrier pairs; no vmcnt(0) in main loop (T4).
__global__ __launch_bounds__(256) void gemm_out(
    const unsigned short* __restrict__ A, const unsigned short* __restrict__ Bm,
    const float* __restrict__ bias, float* __restrict__ out)
{
  // staging: 2 bufs x 12288 u16 = 49,152 B; epilogue Cldf [64][132] f32 aliased
  __shared__ __align__(16) unsigned char smemraw[49152];
  float* Cldf = (float*)smemraw;
  const int t = threadIdx.x, wave = t >> 6, lane = t & 63;
  const int m16 = lane & 15, q4 = lane >> 4;
  const int wm = wave >> 1, wn = wave & 1;                // 2x2 waves: 32 rows x 64 cols each
  const int flat = blockIdx.y * 8 + blockIdx.x;
  const int xcd = flat & 7, bi = flat >> 3;
  const int mb = xcd * 8 + (bi & 7);                      // per XCD: 8 mb x 8 nb
  const int nb = bi >> 3;
  const int srow = lane >> 2, scol = (lane & 3) << 3;
  const unsigned short* pA  = A + (size_t)(mb * 64 + wave * 16 + srow) * KDIM + scol;
  const unsigned short* pB0 = Bm + (size_t)(nb * 128 + wave * 32 + srow) * KDIM + scol;
  const unsigned short* pB1 = pB0 + 16 * KDIM;
  f32x4 acc[2][4];
#pragma unroll
  for (int i_ = 0; i_ < 2; i_++)
#pragma unroll
    for (int j_ = 0; j_ < 4; j_++) acc[i_][j_] = (f32x4){0.f, 0.f, 0.f, 0.f};

  auto stage = [&](int buf, int kt) {
    unsigned short* As = (unsigned short*)smemraw + buf * 12288;
    unsigned short* Bs = As + 4096;
#pragma unroll
    for (int h = 0; h < 2; h++) {
      gload_lds16(pA + kt + h * 32,  As + h * 2048 + (wave * 16) * 32);
      gload_lds16(pB0 + kt + h * 32, Bs + h * 4096 + (wave * 32) * 32);
      gload_lds16(pB1 + kt + h * 32, Bs + h * 4096 + (wave * 32 + 16) * 32);
    }
  };

  stage(0, 0);
  __builtin_amdgcn_sched_barrier(0);
  int cur = 0;
  for (int kt = 0; kt < KDIM; kt += 64) {
    const bool st = (kt + 64 < KDIM);
    if (st) stage(cur ^ 1, kt + 64);                      // 6 fresh loads
    __builtin_amdgcn_sched_barrier(0);
    if (st) asm volatile("s_waitcnt vmcnt(6)" ::: "memory");   // old slab landed, fresh in flight
    else    asm volatile("s_waitcnt vmcnt(0)" ::: "memory");
    __builtin_amdgcn_sched_barrier(0);
    __builtin_amdgcn_s_barrier();
    __builtin_amdgcn_sched_barrier(0);
    const unsigned short* As = (const unsigned short*)smemraw + cur * 12288;
    const unsigned short* Bs = As + 4096;
#pragma unroll
    for (int h = 0; h < 2; h++) {
      short8 af[2], bf[4];
#pragma unroll
      for (int mt = 0; mt < 2; mt++)
        af[mt] = *reinterpret_cast<const short8*>(&As[h * 2048 + (wm * 32 + mt * 16 + m16) * 32 + q4 * 8]);
#pragma unroll
      for (int nt = 0; nt < 4; nt++)
        bf[nt] = *reinterpret_cast<const short8*>(&Bs[h * 4096 + (wn * 64 + nt * 16 + m16) * 32 + q4 * 8]);
#pragma unroll
      for (int mt = 0; mt < 2; mt++)
#pragma unroll
        for (int nt = 0; nt < 4; nt++)
          acc[mt][nt] = __builtin_amdgcn_mfma_f32_16x16x32_bf16(af[mt], bf[nt], acc[mt][nt], 0, 0, 0);
    }
    __builtin_amdgcn_sched_barrier(0);
    __builtin_amdgcn_s_barrier();
    __builtin_amdgcn_sched_barrier(0);
    cur ^= 1;
  }

#pragma unroll
  for (int nt = 0; nt < 4; nt++) {
    int cloc = wn * 64 + nt * 16 + m16;
    float bv = bias[nb * 128 + cloc];
#pragma unroll
    for (int mt = 0; mt < 2; mt++) {
#pragma unroll
      for (int reg = 0; reg < 4; reg++) {
        int rloc = wm * 32 + mt * 16 + q4 * 4 + reg;
        Cldf[rloc * 132 + cloc] = acc[mt][nt][reg] + bv;
      }
    }
  }
  __syncthreads();
  {
    int r = t >> 2, seg = t & 3;   // 64 rows x 4 segments of 32 floats (128 B)
    float* dst = out + (size_t)(mb * 64 + r) * EMBED + nb * 128 + seg * 32;
    const float* srcl = &Cldf[r * 132 + seg * 32];
#pragma unroll
    for (int j = 0; j < 8; j++)
      *reinterpret_cast<float4*>(dst + j * 4) = *reinterpret_cast<const float4*>(srcl + j * 4);
  }
}

// ---------------- banded attention v3: bulk LDS staging, branch-free ----------------
__global__ __launch_bounds__(256, 2) void attn_kernel(
    const unsigned short* __restrict__ q, const unsigned short* __restrict__ k,
    const unsigned short* __restrict__ vTp, unsigned short* __restrict__ vals)
{
  __shared__ __align__(16) unsigned short smem[40960];   // 81,920 B
  unsigned short* Ks = smem;            // [320][64] u16 (40,960 B)
  unsigned short* Vs = smem + 20480;    // [64][320] u16 (40,960 B)
  unsigned short* Pld = smem;           // alias over Ks after QK phase: [4][16][296]

  const int bid = blockIdx.x;
  const int bh = bid & 31, qg = bid >> 5;                // bh-fastest: XCD-local K/V
  const int lane = threadIdx.x & 63, wave = threadIdx.x >> 6;
  const int i0b = qg * 64;
  const int i0 = i0b + wave * 16;
  const int m16 = lane & 15, q4 = lane >> 4;

  // ---- stage K window: 40 KB = 40 wave-issues of 1 KB (10 per wave) ----
  const unsigned short* kbase = k + (size_t)bh * 2048 * 64;
#pragma unroll
  for (int n = 0; n < 10; n++) {
    int idx = (n * 4 + wave) * 64 + lane;      // 0..2559
    int krow = idx >> 3, seg = idx & 7;
    int grow = i0b - 128 + krow;
    grow = grow < 0 ? 0 : (grow > 2047 ? 2047 : grow);
    int lseg = seg ^ (krow & 7);               // store swizzled within 128B row
    gload_lds16(kbase + (size_t)grow * 64 + lseg * 8, Ks + (n * 4 + wave) * 512);
  }
  // ---- stage V^T window: 40 KB, rows of 320 u16 (40 segs of 16B) ----
  const unsigned short* vbase = vTp + (size_t)bh * 64 * SP + i0b;  // col(i0b) == key i0b-128
#pragma unroll
  for (int n = 0; n < 10; n++) {
    int idx = (n * 4 + wave) * 64 + lane;      // 0..2559
    int vrow = idx / 40, rem = idx % 40;
    int l = (rem & ~7) | ((rem & 7) ^ (vrow & 7));
    gload_lds16(vbase + (size_t)vrow * SP + l * 8, Vs + (n * 4 + wave) * 512);
  }

  // q fragments (direct, tiny)
  const unsigned short* qb = q + ((size_t)(bh * 2048 + i0 + m16)) * 64 + q4 * 8;
  short8 aq0 = *reinterpret_cast<const short8*>(qb);
  short8 aq1 = *reinterpret_cast<const short8*>(qb + 32);

  __syncthreads();

  // ---- QK^T + streaming exp, P packed in registers ----
  float sum[4] = {0.f, 0.f, 0.f, 0.f};
  uint32_t pP[18][2];
#pragma unroll
  for (int ct = 0; ct < 18; ct++) {
    int r = (wave + ct) * 16 + m16;            // LDS key row (may run past 320: finite data, masked)
    int js = i0b - 128 + r;                    // global key index
    const unsigned short* kr = Ks + r * 64;
    short8 b0 = *reinterpret_cast<const short8*>(kr + ((q4 ^ (r & 7)) * 8));
    short8 b1 = *reinterpret_cast<const short8*>(kr + (((q4 + 4) ^ (r & 7)) * 8));
    f32x4 a = {0.f, 0.f, 0.f, 0.f};
    a = __builtin_amdgcn_mfma_f32_16x16x32_bf16(aq0, b0, a, 0, 0, 0);
    a = __builtin_amdgcn_mfma_f32_16x16x32_bf16(aq1, b1, a, 0, 0, 0);
    unsigned short pe[4];
#pragma unroll
    for (int reg = 0; reg < 4; reg++) {
      int i = i0 + q4 * 4 + reg;
      bool valid = (js >= 0) && (js < 2048) && (js >= i - 128) && (js <= i + 128);
      float e = valid ? __expf(a[reg] * 0.125f) : 0.0f;
      sum[reg] += e;
      pe[reg] = f2bf(e);
    }
    pP[ct][0] = (uint32_t)pe[0] | ((uint32_t)pe[1] << 16);
    pP[ct][1] = (uint32_t)pe[2] | ((uint32_t)pe[3] << 16);
  }
  float rden[4];
#pragma unroll
  for (int reg = 0; reg < 4; reg++) {
    float s = sum[reg];
    s += __shfl_xor(s, 1);
    s += __shfl_xor(s, 2);
    s += __shfl_xor(s, 4);
    s += __shfl_xor(s, 8);
    rden[reg] = 1.0f / s;
  }

  __syncthreads();   // all Ks reads done; Pld may now overwrite Ks

  unsigned short* Pw = Pld + wave * 16 * 296;
#pragma unroll
  for (int ct = 0; ct < 18; ct++) {
    Pw[(q4 * 4 + 0) * 296 + ct * 16 + m16] = (unsigned short)(pP[ct][0] & 0xFFFF);
    Pw[(q4 * 4 + 1) * 296 + ct * 16 + m16] = (unsigned short)(pP[ct][0] >> 16);
    Pw[(q4 * 4 + 2) * 296 + ct * 16 + m16] = (unsigned short)(pP[ct][1] & 0xFFFF);
    Pw[(q4 * 4 + 3) * 296 + ct * 16 + m16] = (unsigned short)(pP[ct][1] >> 16);
  }
  // own-wave LDS ordering handled by lgkmcnt; no block barrier needed
  short8 ap[9];
#pragma unroll
  for (int kc = 0; kc < 9; kc++)
    ap[kc] = *reinterpret_cast<const short8*>(&Pw[m16 * 296 + kc * 32 + q4 * 8]);

  const int b = bh >> 4, h = bh & 15;
#pragma unroll
  for (int dt = 0; dt < 4; dt++) {
    int vrow = dt * 16 + m16;
    const unsigned short* vr = Vs + vrow * 320;
    f32x4 av = {0.f, 0.f, 0.f, 0.f};
#pragma unroll
    for (int kc = 0; kc < 9; kc++) {
      int jseg = kc * 4 + wave * 2 + q4;       // logical 16B seg within V^T row
      if (jseg > 39) jseg = 39;                // clamp: clamped segs have P==0
      int sseg = (jseg & ~7) | ((jseg & 7) ^ (vrow & 7));
      short8 bv = *reinterpret_cast<const short8*>(vr + sseg * 8);
      av = __builtin_amdgcn_mfma_f32_16x16x32_bf16(ap[kc], bv, av, 0, 0, 0);
    }
#pragma unroll
    for (int reg = 0; reg < 4; reg++)
      Pw[(q4 * 4 + reg) * 296 + dt * 16 + m16] = f2bf(av[reg] * rden[reg]);
  }
  // coalesced O writeout: 4 lanes x 32B per row -> full 128B lines
  {
    int srow = lane >> 2, seg = lane & 3;
    unsigned short* dst = vals + ((size_t)(b * 2048 + i0 + srow)) * 1024 + h * 64 + seg * 16;
    const unsigned short* srcl = &Pw[srow * 296 + seg * 16];
    *reinterpret_cast<short8*>(dst)     = *reinterpret_cast<const short8*>(srcl);
    *reinterpret_cast<short8*>(dst + 8) = *reinterpret_cast<const short8*>(srcl + 8);
  }
}

extern "C" void kernel_launch(void* const* d_in, const int* in_sizes, int n_in,
                              void* d_out, int out_size, void* d_ws, size_t ws_size,
                              hipStream_t stream) {
  const float* x    = (const float*)d_in[0];
  const int*   pm   = (const int*)d_in[1];
  const float* Wqkv = (const float*)d_in[2];
  const float* bqkv = (const float*)d_in[3];
  const float* Wo   = (const float*)d_in[4];
  const float* bo   = (const float*)d_in[5];
  float* out = (float*)d_out;
  char* ws = (char*)d_ws;

  unsigned short* xb    = (unsigned short*)(ws);                 //  8,388,608
  unsigned short* vals  = (unsigned short*)(ws);                 //  reuse (xb dead after gemm_qkv)
  unsigned short* Wqkvb = (unsigned short*)(ws +  8388608);      //  6,291,456
  unsigned short* Wob   = (unsigned short*)(ws + 14680064);      //  2,097,152
  unsigned short* qbuf  = (unsigned short*)(ws + 16777216);      //  8,388,608
  unsigned short* kbuf  = (unsigned short*)(ws + 25165824);      //  8,388,608
  unsigned short* vTp   = (unsigned short*)(ws + 33554432);      //  9,568,256 (ends 43,122,688)

  cvt3_kernel<<<8768, 256, 0, stream>>>(x, Wqkv, Wo, xb, Wqkvb, Wob, vTp);
  gemm_qkv<<<256, 512, 0, stream>>>(xb, Wqkvb, bqkv, pm, qbuf, kbuf, vTp);
  attn_kernel<<<1024, 256, 0, stream>>>(qbuf, kbuf, vTp, vals);
  gemm_out<<<dim3(8, 64), 256, 0, stream>>>(vals, Wob, bo, out);
}